// Round 5
// baseline (2600.081 us; speedup 1.0000x reference)
//
#include <hip/hip_runtime.h>

// ---------------------------------------------------------------------------
// RowLSTM on MI355X — round 11: robust megakernel (conv7 + rnn + out, 240 blk).
//  - R10 hung (container death). Rebuilt with provable safety:
//    * grid 240 <= 256 CUs: every block fits a bare CU -> ALL blocks resident
//      before any completes, regardless of dispatch order. No deadlock cycle.
//    * every cross-block poll is BOUNDED (~60 ms guard): failure => wrong
//      answer + absmax evidence, never a hang.
//    * cross-block data reads (x_ws in rnn, hid_ws in out) are agent-scope
//      relaxed ATOMIC loads -> coherent at device coherence point; immune to
//      cross-XCD and cross-graph-replay L2 staleness. Producers publish via
//      threadfence/release as before. prep re-zeros all flags each replay.
//  - Roles: bid 0-63 rnn (identical arithmetic to R8's 209us kernel);
//    bid 64-239 workers: conv planes y-major (stride 176), then work-steal
//    out planes via global atomic counter; rnn blocks join the steal loop
//    after t=63 so the out tail gets all CUs.
//  - Same-XCD flags: conv/out/rnn blocks of batch b all have bid%8 == b%8.
// Carried: R8 folded layer-0 + c' flag handshake, STP=56, readfirstlane conv,
// packed 64-bit halo atomics, single end-of-row barrier, exp2-prescaled x/W.
// ---------------------------------------------------------------------------

typedef __bf16 bf16x8 __attribute__((ext_vector_type(8)));
typedef __bf16 bf16x4 __attribute__((ext_vector_type(4)));
typedef float  f32x4  __attribute__((ext_vector_type(4)));

#define SC1 (-1.44269504089f)   // -log2(e)
#define SC2 (-2.88539008178f)   // -2 log2(e)

#define STP 56                   // bf16 elems per state column
#define HLS 896                  // hL per-buffer stride = 16*STP
#define CWS 17                   // cwf leading stride
#define POLL_GUARD 65536         // ~60 ms worst-case per poll site

#define BARRIER_LGKM() __asm__ volatile("s_waitcnt lgkmcnt(0)\ns_barrier" ::: "memory")

__device__ __forceinline__ f32x4 aload4(const float* p) {
    f32x4 v;
    v[0] = __hip_atomic_load(p + 0, __ATOMIC_RELAXED, __HIP_MEMORY_SCOPE_AGENT);
    v[1] = __hip_atomic_load(p + 1, __ATOMIC_RELAXED, __HIP_MEMORY_SCOPE_AGENT);
    v[2] = __hip_atomic_load(p + 2, __ATOMIC_RELAXED, __HIP_MEMORY_SCOPE_AGENT);
    v[3] = __hip_atomic_load(p + 3, __ATOMIC_RELAXED, __HIP_MEMORY_SCOPE_AGENT);
    return v;
}

// ---------------------------------------------------------------------------
// wsA layout unchanged from R8 (see comments there). Tail indices:
//  [120832,121856) zero xflag; [121856,122880) zero rowcnt; 122880 zero ocnt.
__global__ __launch_bounds__(256) void prep_kernel(
        const float* __restrict__ wcell, const float* __restrict__ wrh,
        const float* __restrict__ wrc, const float* __restrict__ bcell,
        const float* __restrict__ brh, const float* __restrict__ brc,
        __bf16* __restrict__ wsA, unsigned* __restrict__ xflag,
        unsigned* __restrict__ rowcnt, unsigned* __restrict__ ocnt) {
    int i = blockIdx.x * 256 + threadIdx.x;
    if (i >= 120832) {
        if (i < 121856)       xflag[i - 120832] = 0u;
        else if (i < 122880)  rowcnt[i - 121856] = 0u;
        else if (i == 122880) ocnt[0] = 0u;
        return;
    }
    float val = 0.0f;
    if (i < 35840) {                       // cell a0
        int j = i & 7, lane = (i >> 3) & 63, lm = i >> 9;
        int mt = lm % 10, l = lm / 10;
        int k = (lane >> 4) * 8 + j, m = lane & 15, r = m & 3;
        int row = r * 40 + 4 * mt + (m >> 2);
        val = wcell[(l * 160 + row) * 40 + k] * (r == 3 ? SC2 : SC1);
    } else if (i < 71680) {                // cell a1 ext
        int i2 = i - 35840;
        int j = i2 & 7, lane = (i2 >> 3) & 63, lm = i2 >> 9;
        int mt = lm % 10, l = lm / 10;
        int k = 32 + (lane >> 4) * 8 + j, m = lane & 15, r = m & 3;
        int row = r * 40 + 4 * mt + (m >> 2);
        float s = (r == 3 ? SC2 : SC1);
        if (k < 40)       val = wcell[(l * 160 + row) * 40 + k] * s;
        else if (k == 40) val = bcell[l * 160 + row] * s;
    } else if (i < 80896) {                // conv a0
        int i3 = i - 71680;
        int j = i3 & 7, lane = (i3 >> 3) & 63, idx = i3 >> 9;   // 0..17
        int mtc = idx % 3, t2 = idx / 3, dx = t2 % 3, cv = t2 / 3;
        int k = (lane >> 4) * 8 + j;
        int ch = 16 * mtc + (lane & 15);
        const float* w = cv ? wrc : wrh;       // [40][40][1][3]
        if (ch < 40) val = w[(ch * 40 + k) * 3 + dx];
    } else if (i < 90112) {                // conv a1 ext
        int i4 = i - 80896;
        int j = i4 & 7, lane = (i4 >> 3) & 63, idx = i4 >> 9;
        int mtc = idx % 3, t2 = idx / 3, dx = t2 % 3, cv = t2 / 3;
        int k = 32 + (lane >> 4) * 8 + j;
        int ch = 16 * mtc + (lane & 15);
        if (ch < 40) {
            const float* w = cv ? wrc : wrh;
            if (k < 40)                    val = w[(ch * 40 + k) * 3 + dx];
            else if (k == 40 && dx == 1)   val = (cv ? brc : brh)[ch];
        }
    } else if (i < 105472) {               // F a0: A0·Wrh_dx, k=0..31
        int i5 = i - 90112;
        int j = i5 & 7, lane = (i5 >> 3) & 63, idx = i5 >> 9;   // 0..29
        int mt = idx % 10, dx = idx / 10;
        int k = (lane >> 4) * 8 + j, m = lane & 15, r = m & 3;
        int row = r * 40 + 4 * mt + (m >> 2);
        float s = (r == 3 ? SC2 : SC1);
        float acc = 0.0f;
        for (int mm = 0; mm < 40; mm++)
            acc = __builtin_fmaf(wcell[row * 40 + mm],
                                 wrh[(mm * 40 + k) * 3 + dx], acc);
        val = acc * s;
    } else {                               // F a1 ext, k=32..47
        int i6 = i - 105472;
        int j = i6 & 7, lane = (i6 >> 3) & 63, idx = i6 >> 9;
        int mt = idx % 10, dx = idx / 10;
        int k = 32 + (lane >> 4) * 8 + j, m = lane & 15, r = m & 3;
        int row = r * 40 + 4 * mt + (m >> 2);
        float s = (r == 3 ? SC2 : SC1);
        if (k < 40) {
            float acc = 0.0f;
            for (int mm = 0; mm < 40; mm++)
                acc = __builtin_fmaf(wcell[row * 40 + mm],
                                     wrh[(mm * 40 + k) * 3 + dx], acc);
            val = acc * s;
        } else if (k == 40 && dx == 1) {
            float acc = bcell[row];        // b_cell0 + A0·b_rh
            for (int mm = 0; mm < 40; mm++)
                acc = __builtin_fmaf(wcell[row * 40 + mm], brh[mm], acc);
            val = acc * s;
        }
    }
    wsA[i] = (__bf16)val;
}

// ---------------------------------------------------------------------------
// Fused kernel: 240 blocks x 640 threads (all co-resident by construction).
//  bid 0..63   : rnn  (bid = g*16 + b)
//  bid 64..239 : conv planes p = (bid-64), +176, ... (p -> y=p>>4, b=p&15)
//  then ALL blocks: out plane work-steal via ocnt.
// x_ws (float, PRE-SCALED): [b][t][g4][mt10][q4][l16][gate4]
// halo_ws (u64): [bid][side2][parity2][ch40]; word = tag<<32 | c16<<16 | h16.
__global__ __launch_bounds__(640, 3) void fused_kernel(
        const float* __restrict__ inp, const float* __restrict__ tgt,
        const float* __restrict__ w_is, const float* __restrict__ b_is,
        const float* __restrict__ w_cis, const float* __restrict__ b_cis,
        float* __restrict__ x_ws, const __bf16* __restrict__ wsA,
        float* __restrict__ hid_ws, unsigned long long* __restrict__ halo_ws,
        unsigned* __restrict__ xflag, unsigned* __restrict__ rowcnt,
        unsigned* __restrict__ ocnt,
        const float* __restrict__ w_out, const float* __restrict__ b_out,
        float* __restrict__ out) {
    __shared__ __align__(16) unsigned char smem[53760];
    __shared__ unsigned cflag[4];
    __shared__ unsigned oplane;
    const int bid = blockIdx.x;
    const int tid = threadIdx.x;

    if (bid < 64) {
        // ================= rnn role (R8 structure, 10 waves) =================
        __bf16* hC  = (__bf16*)smem;            // [18][STP]+pad, col0/17 halos
        __bf16* cC  = (__bf16*)(smem + 4096);
        __bf16* hL  = (__bf16*)(smem + 8192);   // [2][16][STP]+pad
        float*  cwf = (float*)(smem + 16384);   // [40][CWS]

        const int g = bid >> 4, b = bid & 15;
        const int wv = tid >> 6, lane = tid & 63;
        const int q = lane >> 4, l16 = lane & 15, cc = 4 * wv + q;
        const int W0 = g * 16;

        // ---- init LDS ----
        for (int i = tid; i < 536; i += 640) {
            ((float*)hC)[i] = 0.0f;
            ((float*)cC)[i] = 0.0f;
        }
        for (int i = tid; i < 912; i += 640)
            ((float*)hL)[i] = 0.0f;
        for (int i = tid; i < 40 * CWS; i += 640) cwf[i] = 0.0f;
        if (tid < 4) cflag[tid] = 0xFFFFFFFFu;
        __syncthreads();
        if (tid < 18) { hC[tid * STP + 40] = (__bf16)1.0f; cC[tid * STP + 40] = (__bf16)1.0f; }
        if (tid < 32) hL[(tid >> 4) * HLS + (tid & 15) * STP + 40] = (__bf16)1.0f;
        __syncthreads();

        // ---- preload fragments ----
        bf16x8 a0c[6], a1c[6];                  // cell layers 1..6
#pragma unroll
        for (int l = 1; l < 7; l++) {
            a0c[l - 1] = *(const bf16x8*)&wsA[((l * 10 + wv) * 64 + lane) * 8];
            a1c[l - 1] = *(const bf16x8*)&wsA[35840 + ((l * 10 + wv) * 64 + lane) * 8];
        }
        bf16x8 f0c[3], f1c[3];                  // folded A0·Wrh_dx (layer 0)
#pragma unroll
        for (int dx = 0; dx < 3; dx++) {
            f0c[dx] = *(const bf16x8*)&wsA[90112 + ((dx * 10 + wv) * 64 + lane) * 8];
            f1c[dx] = *(const bf16x8*)&wsA[105472 + ((dx * 10 + wv) * 64 + lane) * 8];
        }
        bf16x8 cva0[3], cva1[3];                // Wrc conv (c' producers)
        if (wv >= 3 && wv < 6) {
            int mtc = wv - 3;
#pragma unroll
            for (int dx = 0; dx < 3; dx++) {
                int it = (3 + dx) * 3 + mtc;    // cv=1 tiles
                cva0[dx] = *(const bf16x8*)&wsA[71680 + (it * 64 + lane) * 8];
                cva1[dx] = *(const bf16x8*)&wsA[80896 + (it * 64 + lane) * 8];
            }
        }

        float c_reg = 0.0f;
        const size_t xstride = 10240;   // floats per (b,t)
        const size_t xbase0 = (size_t)(b * 64) * xstride
            + (((size_t)g * 10 + wv) * 4 + q) * 64 + l16 * 4;
        // wait for conv of row 0 (bounded; data read via coherent atomics)
        {
            int gk = 0;
            while (__hip_atomic_load(&xflag[b * 64], __ATOMIC_ACQUIRE,
                                     __HIP_MEMORY_SCOPE_AGENT) == 0u) {
                if (++gk > POLL_GUARD) break;
                __builtin_amdgcn_s_sleep(2);
            }
        }
        f32x4 xv = aload4(&x_ws[xbase0]);

        for (int t = 0; t < 64; t++) {
            // ---- prefetch x for row t+1 (bounded poll + atomic loads) ----
            f32x4 xn = xv;
            if (t < 63) {
                int gk = 0;
                while (__hip_atomic_load(&xflag[b * 64 + t + 1], __ATOMIC_ACQUIRE,
                                         __HIP_MEMORY_SCOPE_AGENT) == 0u) {
                    if (++gk > POLL_GUARD) break;
                    __builtin_amdgcn_s_sleep(2);
                }
                xn = aload4(&x_ws[xbase0 + (size_t)(t + 1) * xstride]);
            }

            // ---- c' producers (waves 3-5): conv c, publish via flag ----
            if (wv >= 3 && wv < 6) {
                f32x4 ac = f32x4{0.f, 0.f, 0.f, 0.f};
#pragma unroll
                for (int dx = 0; dx < 3; dx++) {
                    bf16x8 b0 = *(const bf16x8*)&cC[(l16 + dx) * STP + q * 8];
                    bf16x8 b1 = *(const bf16x8*)&cC[(l16 + dx) * STP + 32 + q * 8];
                    ac = __builtin_amdgcn_mfma_f32_16x16x32_bf16(cva0[dx], b0, ac, 0, 0, 0);
                    ac = __builtin_amdgcn_mfma_f32_16x16x32_bf16(cva1[dx], b1, ac, 0, 0, 0);
                }
                int mtc = wv - 3, ch0 = 16 * mtc + 4 * q;
                if (ch0 < 40) {
#pragma unroll
                    for (int r = 0; r < 4; r++) cwf[(ch0 + r) * CWS + l16] = ac[r];
                }
                __asm__ volatile("s_waitcnt lgkmcnt(0)" ::: "memory");
                if (lane == 0)
                    __hip_atomic_store(&cflag[mtc], (unsigned)t,
                                       __ATOMIC_RELAXED, __HIP_MEMORY_SCOPE_WORKGROUP);
            }

            // ---- layer-0 gate MFMAs: folded conv+1x1 straight from hC ----
            f32x4 acc0 = f32x4{0.f, 0.f, 0.f, 0.f};
#pragma unroll
            for (int dx = 0; dx < 3; dx++) {
                bf16x8 b0 = *(const bf16x8*)&hC[(l16 + dx) * STP + q * 8];
                bf16x8 b1 = *(const bf16x8*)&hC[(l16 + dx) * STP + 32 + q * 8];
                acc0 = __builtin_amdgcn_mfma_f32_16x16x32_bf16(f0c[dx], b0, acc0, 0, 0, 0);
                acc0 = __builtin_amdgcn_mfma_f32_16x16x32_bf16(f1c[dx], b1, acc0, 0, 0, 0);
            }
            // ---- wait for c' (usually 0 iterations; intra-block, proven) ----
            {
                int jj = wv >> 2;
                while (__hip_atomic_load(&cflag[jj], __ATOMIC_RELAXED,
                                         __HIP_MEMORY_SCOPE_WORKGROUP) != (unsigned)t)
                    __builtin_amdgcn_s_sleep(1);
                __asm__ volatile("" ::: "memory");
            }

            // ---- 7 layers (l0 uses acc0; l1..6 read hL) ----
#pragma unroll
            for (int l = 0; l < 7; l++) {
                f32x4 acc;
                if (l == 0) {
                    acc = acc0;
                    c_reg = cwf[cc * CWS + l16];
                } else {
                    const __bf16* hb = &hL[(l & 1) * HLS];
                    bf16x8 b0 = *(const bf16x8*)&hb[l16 * STP + q * 8];
                    bf16x8 b1 = *(const bf16x8*)&hb[l16 * STP + 32 + q * 8];
                    acc = __builtin_amdgcn_mfma_f32_16x16x32_bf16(
                        a0c[l - 1], b0, f32x4{0.f, 0.f, 0.f, 0.f}, 0, 0, 0);
                    acc = __builtin_amdgcn_mfma_f32_16x16x32_bf16(a1c[l - 1], b1, acc, 0, 0, 0);
                }
                float Ei = __builtin_amdgcn_exp2f(fminf(acc[0] + xv[0], 44.f));
                float Ef = __builtin_amdgcn_exp2f(fminf(acc[1] + xv[1], 44.f));
                float Eo = __builtin_amdgcn_exp2f(fminf(acc[2] + xv[2], 44.f));
                float Eg = __builtin_amdgcn_exp2f(fminf(acc[3] + xv[3], 44.f));
                float f = __builtin_amdgcn_rcpf(1.0f + Ef);
                float ig = (1.0f - Eg) * __builtin_amdgcn_rcpf((1.0f + Ei) * (1.0f + Eg));
                float c = __builtin_fmaf(f, c_reg, ig);
                c_reg = c;
                float Ec = __builtin_amdgcn_exp2f(fminf(SC2 * c, 44.f));
                float h = (1.0f - Ec) * __builtin_amdgcn_rcpf((1.0f + Eo) * (1.0f + Ec));
                if (l < 6) {
                    hL[((l + 1) & 1) * HLS + l16 * STP + cc] = (__bf16)h;
                    BARRIER_LGKM();
                } else {
                    hC[(l16 + 1) * STP + cc] = (__bf16)h;
                    cC[(l16 + 1) * STP + cc] = (__bf16)c;
                    hid_ws[(size_t)((b * 64 + t) * 40 + cc) * 64 + W0 + l16] = h;
                    if (t < 63) {
                        unsigned short h16 = __builtin_bit_cast(unsigned short, (__bf16)h);
                        unsigned short c16 = __builtin_bit_cast(unsigned short, (__bf16)c);
                        unsigned long long v = ((unsigned long long)(unsigned)t << 32)
                            | ((unsigned)c16 << 16) | (unsigned)h16;
                        if (l16 == 0 && g > 0)
                            __hip_atomic_store(
                                &halo_ws[((bid * 2 + 0) * 2 + (t & 1)) * 40 + cc], v,
                                __ATOMIC_RELAXED, __HIP_MEMORY_SCOPE_AGENT);
                        if (l16 == 15 && g < 3)
                            __hip_atomic_store(
                                &halo_ws[((bid * 2 + 1) * 2 + (t & 1)) * 40 + cc], v,
                                __ATOMIC_RELAXED, __HIP_MEMORY_SCOPE_AGENT);
                    }
                    // publish this wave's hid row-slice (release drains the
                    // wave's prior global stores to the coherence point)
                    if (lane == 0)
                        __hip_atomic_fetch_add(&rowcnt[b * 64 + t], 1u,
                                               __ATOMIC_RELEASE, __HIP_MEMORY_SCOPE_AGENT);
                }
            }

            // ---- ingest neighbor halos for row t+1 (wv8: left, wv9: right) --
            if (t < 63) {
                if (wv == 8 && g > 0 && lane < 40) {
                    const unsigned long long* src =
                        &halo_ws[(((bid - 16) * 2 + 1) * 2 + (t & 1)) * 40 + lane];
                    unsigned long long v = __hip_atomic_load(
                        src, __ATOMIC_RELAXED, __HIP_MEMORY_SCOPE_AGENT);
                    while ((unsigned)(v >> 32) != (unsigned)t) {
                        __builtin_amdgcn_s_sleep(1);
                        v = __hip_atomic_load(src, __ATOMIC_RELAXED,
                                              __HIP_MEMORY_SCOPE_AGENT);
                    }
                    hC[lane] = __builtin_bit_cast(__bf16, (unsigned short)(v & 0xffffu));
                    cC[lane] = __builtin_bit_cast(__bf16, (unsigned short)((v >> 16) & 0xffffu));
                }
                if (wv == 9 && g < 3 && lane < 40) {
                    const unsigned long long* src =
                        &halo_ws[(((bid + 16) * 2 + 0) * 2 + (t & 1)) * 40 + lane];
                    unsigned long long v = __hip_atomic_load(
                        src, __ATOMIC_RELAXED, __HIP_MEMORY_SCOPE_AGENT);
                    while ((unsigned)(v >> 32) != (unsigned)t) {
                        __builtin_amdgcn_s_sleep(1);
                        v = __hip_atomic_load(src, __ATOMIC_RELAXED,
                                              __HIP_MEMORY_SCOPE_AGENT);
                    }
                    hC[17 * STP + lane] = __builtin_bit_cast(__bf16, (unsigned short)(v & 0xffffu));
                    cC[17 * STP + lane] = __builtin_bit_cast(__bf16, (unsigned short)((v >> 16) & 0xffffu));
                }
            }
            BARRIER_LGKM();   // single end-of-row barrier
            xv = xn;
        }
    } else {
        // ================= conv role: planes p, p+176, ... =================
        for (int p = bid - 64; p < 1024; p += 176) {
            const int y = p >> 4, b = p & 15;
            const int j = tid >> 6, w = tid & 63;   // j = wave = mt index
            const float* ib = inp + b * 4096;
            const float* tb = tgt + b * 4096;
            float pin[7][7], ptg[4][7];
#pragma unroll
            for (int dy = 0; dy < 7; dy++) {
                int yy = y + dy - 3;
#pragma unroll
                for (int dx = 0; dx < 7; dx++) {
                    int xx = w + dx - 3;
                    bool ok = (yy >= 0 && yy < 64 && xx >= 0 && xx < 64);
                    pin[dy][dx] = ok ? ib[yy * 64 + xx] : 0.0f;
                    if (dy < 4) ptg[dy][dx] = ok ? tb[yy * 64 + xx] : 0.0f;
                }
            }
            int g = w >> 4, l16 = w & 15;
#pragma unroll 1
            for (int qq = 0; qq < 4; qq++) {
                int cc = 4 * j + qq;
                int ccu = __builtin_amdgcn_readfirstlane(cc);   // wave-uniform
                float a0 = b_cis[ccu], a1 = b_cis[40 + ccu];
                float a2 = b_is[ccu], a3 = b_is[40 + ccu];
                const float* w0 = w_cis + ccu * 49;
                const float* w1 = w_cis + (40 + ccu) * 49;
                const float* w2 = w_is + ccu * 49;
                const float* w3 = w_is + (40 + ccu) * 49;
#pragma unroll
                for (int dy = 0; dy < 7; dy++)
#pragma unroll
                    for (int dx = 0; dx < 7; dx++) {
                        a0 = __builtin_fmaf(w0[dy * 7 + dx], pin[dy][dx], a0);
                        a1 = __builtin_fmaf(w1[dy * 7 + dx], pin[dy][dx], a1);
                    }
#pragma unroll
                for (int dy = 0; dy < 3; dy++)
#pragma unroll
                    for (int dx = 0; dx < 7; dx++) {
                        a2 = __builtin_fmaf(w2[dy * 7 + dx], ptg[dy][dx], a2);
                        a3 = __builtin_fmaf(w3[dy * 7 + dx], ptg[dy][dx], a3);
                    }
#pragma unroll
                for (int dx = 0; dx < 3; dx++) {
                    a2 = __builtin_fmaf(w2[21 + dx], ptg[3][dx], a2);
                    a3 = __builtin_fmaf(w3[21 + dx], ptg[3][dx], a3);
                }
                size_t idx = (size_t)((((b * 64 + y) * 4 + g) * 10 + j) * 4 + qq) * 64
                             + l16 * 4;
                *(f32x4*)&x_ws[idx] = f32x4{a0 * SC1, a1 * SC1, a2 * SC1, a3 * SC2};
            }
            __threadfence();           // each thread drains its stores
            __syncthreads();           // all threads drained
            if (tid == 0)
                __hip_atomic_store(&xflag[b * 64 + y], 1u,
                                   __ATOMIC_RELEASE, __HIP_MEMORY_SCOPE_AGENT);
        }
    }

    // ================= all blocks: out plane work-steal =================
    float* wlds = (float*)smem;             // [40][264] transposed
    float* hlds = (float*)(smem + 42240);   // [40][64]
    __syncthreads();                        // rnn: all waves done with smem
    for (int i = tid; i < 10240; i += 640) {
        int o = i / 40, k = i - o * 40;
        wlds[k * 264 + o] = w_out[i];
    }
    while (true) {
        if (tid == 0)
            oplane = __hip_atomic_fetch_add(ocnt, 1u, __ATOMIC_RELAXED,
                                            __HIP_MEMORY_SCOPE_AGENT);
        __syncthreads();                    // oplane visible; prev GEMM done
        unsigned p = oplane;
        if (p >= 1024u) break;
        const int y = p >> 4, b = p & 15;
        if (tid == 0) {
            int gk = 0;
            while (__hip_atomic_load(&rowcnt[b * 64 + y], __ATOMIC_ACQUIRE,
                                     __HIP_MEMORY_SCOPE_AGENT) < 40u) {
                if (++gk > POLL_GUARD) break;
                __builtin_amdgcn_s_sleep(32);
            }
        }
        __syncthreads();                    // row ready
        const float* hbp = hid_ws + (size_t)(b * 64 + y) * 2560;
        for (int i = tid; i < 2560; i += 640)
            hlds[i] = __hip_atomic_load(&hbp[i], __ATOMIC_RELAXED,
                                        __HIP_MEMORY_SCOPE_AGENT);
        __syncthreads();

        if (tid < 256) {
            int tn = tid & 7, tm = tid >> 3;
            int wbase = tn * 8, obase = tm * 8;
            float acc[8][8];
#pragma unroll
            for (int io = 0; io < 8; io++)
#pragma unroll
                for (int iw = 0; iw < 8; iw++) acc[io][iw] = 0.0f;

            for (int k = 0; k < 40; k++) {
                f32x4 hA = *(const f32x4*)&hlds[k * 64 + wbase];
                f32x4 hB = *(const f32x4*)&hlds[k * 64 + wbase + 4];
                f32x4 wA = *(const f32x4*)&wlds[k * 264 + obase];
                f32x4 wB = *(const f32x4*)&wlds[k * 264 + obase + 4];
#pragma unroll
                for (int io = 0; io < 8; io++) {
                    float wo = (io < 4) ? wA[io] : wB[io - 4];
#pragma unroll
                    for (int iw = 0; iw < 8; iw++) {
                        float hx = (iw < 4) ? hA[iw] : hB[iw - 4];
                        acc[io][iw] = __builtin_fmaf(wo, hx, acc[io][iw]);
                    }
                }
            }
#pragma unroll
            for (int io = 0; io < 8; io++) {
                int o = obase + io;
                float bo = b_out[o];
                f32x4 s0, s1;
#pragma unroll
                for (int iw = 0; iw < 4; iw++)
                    s0[iw] = fmaxf(acc[io][iw] + bo, 0.0f);
#pragma unroll
                for (int iw = 0; iw < 4; iw++)
                    s1[iw] = fmaxf(acc[io][iw + 4] + bo, 0.0f);
                float* ob = out + (size_t)((b * 256 + o) * 64 + y) * 64 + wbase;
                *(f32x4*)ob = s0;
                *(f32x4*)(ob + 4) = s1;
            }
        }
    }
}

// ---------------------------------------------------------------------------
extern "C" void kernel_launch(void* const* d_in, const int* in_sizes, int n_in,
                              void* d_out, int out_size, void* d_ws,
                              size_t ws_size, hipStream_t stream) {
    const float* input  = (const float*)d_in[0];
    const float* target = (const float*)d_in[1];
    const float* w_is   = (const float*)d_in[2];
    const float* b_is   = (const float*)d_in[3];
    const float* w_cis  = (const float*)d_in[4];
    const float* b_cis  = (const float*)d_in[5];
    const float* w_rh   = (const float*)d_in[6];
    const float* b_rh   = (const float*)d_in[7];
    const float* w_rc   = (const float*)d_in[8];
    const float* b_rc   = (const float*)d_in[9];
    const float* w_cell = (const float*)d_in[10];
    const float* b_cell = (const float*)d_in[11];
    const float* w_out  = (const float*)d_in[12];
    const float* b_out  = (const float*)d_in[13];
    float* out = (float*)d_out;

    char* ws = (char*)d_ws;
    float*              x_ws    = (float*)ws;                        // 41,943,040 B
    float*              hid_ws  = (float*)(ws + 41943040);           // 10,485,760 B
    __bf16*             wsA     = (__bf16*)(ws + 52428800);          //    241,664 B
    unsigned long long* halo_ws = (unsigned long long*)(ws + 52670464); // 81,920 B
    unsigned*           xflag   = (unsigned*)(ws + 52752384);        //      4,096 B
    unsigned*           rowcnt  = (unsigned*)(ws + 52756480);        //      4,096 B
    unsigned*           ocnt    = (unsigned*)(ws + 52760576);        //          4 B

    prep_kernel<<<481, 256, 0, stream>>>(w_cell, w_rh, w_rc, b_cell, b_rh,
                                         b_rc, wsA, xflag, rowcnt, ocnt);
    fused_kernel<<<240, 640, 0, stream>>>(input, target, w_is, b_is, w_cis,
                                          b_cis, x_ws, wsA, hid_ws, halo_ws,
                                          xflag, rowcnt, ocnt, w_out, b_out,
                                          out);
}

// Round 6
// 458.406 us; speedup vs baseline: 5.6720x; 5.6720x over previous
//
#include <hip/hip_runtime.h>

// ---------------------------------------------------------------------------
// RowLSTM on MI355X — round 12: conv7 fused into rnn dispatch via ONE gate.
//  - R11 diagnosis: per-row per-wave agent-scope ACQUIRE polls (vmcnt(0) drain
//    + cache-inv per acquire) inside the rnn hot loop + no 1-block/CU
//    guarantee => 7x stall. Fix: fuse ONLY conv, with a single start gate.
//  - Fused dispatch: 240 blocks x 640 thr, LDS padded 83KB -> 1 block/CU
//    guaranteed, all 240 co-resident (<=256 CUs). Workers (bid 64-239):
//    ~6 conv planes each (~10us), threadfence, one release fetch_add(xcnt),
//    exit. rnn blocks (bid 0-63): LDS init + fragment preload, ONE bounded
//    acquire gate on xcnt==176, then the BYTE-IDENTICAL R8 row loop with
//    plain x loads (no atomics/polls/acquires in the hot loop).
//  - Stale-cache safety: rnn never reads x_ws before the gate within this
//    dispatch; dispatch-boundary CP invalidation covers graph replays.
//  - out remains a separate dispatch (R2's proven kernel, stream-ordered).
// Carried: R8 folded layer-0 + c' flag handshake, STP=56, readfirstlane conv,
// packed 64-bit halo atomics, single end-of-row barrier, exp2-prescaled x/W.
// ---------------------------------------------------------------------------

typedef __bf16 bf16x8 __attribute__((ext_vector_type(8)));
typedef __bf16 bf16x4 __attribute__((ext_vector_type(4)));
typedef float  f32x4  __attribute__((ext_vector_type(4)));

#define SC1 (-1.44269504089f)   // -log2(e)
#define SC2 (-2.88539008178f)   // -2 log2(e)

#define STP 56                   // bf16 elems per state column
#define HLS 896                  // hL per-buffer stride = 16*STP
#define CWS 17                   // cwf leading stride
#define NWRK 176u                // conv worker blocks

#define BARRIER_LGKM() __asm__ volatile("s_waitcnt lgkmcnt(0)\ns_barrier" ::: "memory")

// ---------------------------------------------------------------------------
// wsA layout (bf16 elems), unchanged from R8:
//  [0,35840) cell a0; [35840,71680) cell a1x; [71680,80896) conv a0;
//  [80896,90112) conv a1x; [90112,105472) F a0; [105472,120832) F a1x.
//  i == 120832: zero xcnt.
__global__ __launch_bounds__(256) void prep_kernel(
        const float* __restrict__ wcell, const float* __restrict__ wrh,
        const float* __restrict__ wrc, const float* __restrict__ bcell,
        const float* __restrict__ brh, const float* __restrict__ brc,
        __bf16* __restrict__ wsA, unsigned* __restrict__ xcnt) {
    int i = blockIdx.x * 256 + threadIdx.x;
    if (i >= 120832) {
        if (i == 120832) xcnt[0] = 0u;
        return;
    }
    float val = 0.0f;
    if (i < 35840) {                       // cell a0
        int j = i & 7, lane = (i >> 3) & 63, lm = i >> 9;
        int mt = lm % 10, l = lm / 10;
        int k = (lane >> 4) * 8 + j, m = lane & 15, r = m & 3;
        int row = r * 40 + 4 * mt + (m >> 2);
        val = wcell[(l * 160 + row) * 40 + k] * (r == 3 ? SC2 : SC1);
    } else if (i < 71680) {                // cell a1 ext
        int i2 = i - 35840;
        int j = i2 & 7, lane = (i2 >> 3) & 63, lm = i2 >> 9;
        int mt = lm % 10, l = lm / 10;
        int k = 32 + (lane >> 4) * 8 + j, m = lane & 15, r = m & 3;
        int row = r * 40 + 4 * mt + (m >> 2);
        float s = (r == 3 ? SC2 : SC1);
        if (k < 40)       val = wcell[(l * 160 + row) * 40 + k] * s;
        else if (k == 40) val = bcell[l * 160 + row] * s;
    } else if (i < 80896) {                // conv a0
        int i3 = i - 71680;
        int j = i3 & 7, lane = (i3 >> 3) & 63, idx = i3 >> 9;   // 0..17
        int mtc = idx % 3, t2 = idx / 3, dx = t2 % 3, cv = t2 / 3;
        int k = (lane >> 4) * 8 + j;
        int ch = 16 * mtc + (lane & 15);
        const float* w = cv ? wrc : wrh;       // [40][40][1][3]
        if (ch < 40) val = w[(ch * 40 + k) * 3 + dx];
    } else if (i < 90112) {                // conv a1 ext
        int i4 = i - 80896;
        int j = i4 & 7, lane = (i4 >> 3) & 63, idx = i4 >> 9;
        int mtc = idx % 3, t2 = idx / 3, dx = t2 % 3, cv = t2 / 3;
        int k = 32 + (lane >> 4) * 8 + j;
        int ch = 16 * mtc + (lane & 15);
        if (ch < 40) {
            const float* w = cv ? wrc : wrh;
            if (k < 40)                    val = w[(ch * 40 + k) * 3 + dx];
            else if (k == 40 && dx == 1)   val = (cv ? brc : brh)[ch];
        }
    } else if (i < 105472) {               // F a0: A0·Wrh_dx, k=0..31
        int i5 = i - 90112;
        int j = i5 & 7, lane = (i5 >> 3) & 63, idx = i5 >> 9;   // 0..29
        int mt = idx % 10, dx = idx / 10;
        int k = (lane >> 4) * 8 + j, m = lane & 15, r = m & 3;
        int row = r * 40 + 4 * mt + (m >> 2);
        float s = (r == 3 ? SC2 : SC1);
        float acc = 0.0f;
        for (int mm = 0; mm < 40; mm++)
            acc = __builtin_fmaf(wcell[row * 40 + mm],
                                 wrh[(mm * 40 + k) * 3 + dx], acc);
        val = acc * s;
    } else {                               // F a1 ext, k=32..47
        int i6 = i - 105472;
        int j = i6 & 7, lane = (i6 >> 3) & 63, idx = i6 >> 9;
        int mt = idx % 10, dx = idx / 10;
        int k = 32 + (lane >> 4) * 8 + j, m = lane & 15, r = m & 3;
        int row = r * 40 + 4 * mt + (m >> 2);
        float s = (r == 3 ? SC2 : SC1);
        if (k < 40) {
            float acc = 0.0f;
            for (int mm = 0; mm < 40; mm++)
                acc = __builtin_fmaf(wcell[row * 40 + mm],
                                     wrh[(mm * 40 + k) * 3 + dx], acc);
            val = acc * s;
        } else if (k == 40 && dx == 1) {
            float acc = bcell[row];        // b_cell0 + A0·b_rh
            for (int mm = 0; mm < 40; mm++)
                acc = __builtin_fmaf(wcell[row * 40 + mm], brh[mm], acc);
            val = acc * s;
        }
    }
    wsA[i] = (__bf16)val;
}

// ---------------------------------------------------------------------------
// Fused conv+rnn: 240 blocks x 640 threads, 1 block/CU (83KB LDS pad).
//  bid 0..63   : rnn (bid = g*16 + b), gated on xcnt==176.
//  bid 64..239 : conv planes p=(bid-64)+176k, p=y*16+b (y-major pacing).
// x_ws (float, PRE-SCALED): [b][t][g4][mt10][q4][l16][gate4]
// halo_ws (u64): [bid][side2][parity2][ch40]; word = tag<<32 | c16<<16 | h16.
__global__ __launch_bounds__(640, 1) void fused_kernel(
        const float* __restrict__ inp, const float* __restrict__ tgt,
        const float* __restrict__ w_is, const float* __restrict__ b_is,
        const float* __restrict__ w_cis, const float* __restrict__ b_cis,
        float* __restrict__ x_ws, const __bf16* __restrict__ wsA,
        float* __restrict__ hid_ws, unsigned long long* __restrict__ halo_ws,
        unsigned* __restrict__ xcnt) {
    __shared__ __align__(16) unsigned char smem[83968];  // 1 block/CU pad
    __shared__ unsigned cflag[4];
    const int bid = blockIdx.x;
    const int tid = threadIdx.x;

    if (bid >= 64) {
        // ================= conv role: planes p, p+176, ... =================
        for (int p = bid - 64; p < 1024; p += 176) {
            const int y = p >> 4, b = p & 15;
            const int j = tid >> 6, w = tid & 63;   // j = wave = mt index
            const float* ib = inp + b * 4096;
            const float* tb = tgt + b * 4096;
            float pin[7][7], ptg[4][7];
#pragma unroll
            for (int dy = 0; dy < 7; dy++) {
                int yy = y + dy - 3;
#pragma unroll
                for (int dx = 0; dx < 7; dx++) {
                    int xx = w + dx - 3;
                    bool ok = (yy >= 0 && yy < 64 && xx >= 0 && xx < 64);
                    pin[dy][dx] = ok ? ib[yy * 64 + xx] : 0.0f;
                    if (dy < 4) ptg[dy][dx] = ok ? tb[yy * 64 + xx] : 0.0f;
                }
            }
            int g = w >> 4, l16 = w & 15;
#pragma unroll 1
            for (int qq = 0; qq < 4; qq++) {
                int cc = 4 * j + qq;
                int ccu = __builtin_amdgcn_readfirstlane(cc);   // wave-uniform
                float a0 = b_cis[ccu], a1 = b_cis[40 + ccu];
                float a2 = b_is[ccu], a3 = b_is[40 + ccu];
                const float* w0 = w_cis + ccu * 49;
                const float* w1 = w_cis + (40 + ccu) * 49;
                const float* w2 = w_is + ccu * 49;
                const float* w3 = w_is + (40 + ccu) * 49;
#pragma unroll
                for (int dy = 0; dy < 7; dy++)
#pragma unroll
                    for (int dx = 0; dx < 7; dx++) {
                        a0 = __builtin_fmaf(w0[dy * 7 + dx], pin[dy][dx], a0);
                        a1 = __builtin_fmaf(w1[dy * 7 + dx], pin[dy][dx], a1);
                    }
#pragma unroll
                for (int dy = 0; dy < 3; dy++)
#pragma unroll
                    for (int dx = 0; dx < 7; dx++) {
                        a2 = __builtin_fmaf(w2[dy * 7 + dx], ptg[dy][dx], a2);
                        a3 = __builtin_fmaf(w3[dy * 7 + dx], ptg[dy][dx], a3);
                    }
#pragma unroll
                for (int dx = 0; dx < 3; dx++) {
                    a2 = __builtin_fmaf(w2[21 + dx], ptg[3][dx], a2);
                    a3 = __builtin_fmaf(w3[21 + dx], ptg[3][dx], a3);
                }
                size_t idx = (size_t)((((b * 64 + y) * 4 + g) * 10 + j) * 4 + qq) * 64
                             + l16 * 4;
                *(f32x4*)&x_ws[idx] = f32x4{a0 * SC1, a1 * SC1, a2 * SC1, a3 * SC2};
            }
        }
        __threadfence();               // drain + write back all plane stores
        __syncthreads();               // every thread's fence done
        if (tid == 0)
            __hip_atomic_fetch_add(xcnt, 1u, __ATOMIC_RELEASE,
                                   __HIP_MEMORY_SCOPE_AGENT);
        return;                        // worker exits; CU freed for nothing
    }

    // ================= rnn role (R8 structure, 10 waves) =================
    __bf16* hC  = (__bf16*)smem;            // [18][STP]+pad, col0/17 halos
    __bf16* cC  = (__bf16*)(smem + 4096);
    __bf16* hL  = (__bf16*)(smem + 8192);   // [2][16][STP]+pad
    float*  cwf = (float*)(smem + 16384);   // [40][CWS]

    const int g = bid >> 4, b = bid & 15;
    const int wv = tid >> 6, lane = tid & 63;
    const int q = lane >> 4, l16 = lane & 15, cc = 4 * wv + q;
    const int W0 = g * 16;

    // ---- init LDS (overlaps conv phase) ----
    for (int i = tid; i < 536; i += 640) {
        ((float*)hC)[i] = 0.0f;
        ((float*)cC)[i] = 0.0f;
    }
    for (int i = tid; i < 912; i += 640)
        ((float*)hL)[i] = 0.0f;
    for (int i = tid; i < 40 * CWS; i += 640) cwf[i] = 0.0f;
    if (tid < 4) cflag[tid] = 0xFFFFFFFFu;
    __syncthreads();
    if (tid < 18) { hC[tid * STP + 40] = (__bf16)1.0f; cC[tid * STP + 40] = (__bf16)1.0f; }
    if (tid < 32) hL[(tid >> 4) * HLS + (tid & 15) * STP + 40] = (__bf16)1.0f;
    __syncthreads();

    // ---- preload fragments (overlaps conv phase) ----
    bf16x8 a0c[6], a1c[6];                  // cell layers 1..6
#pragma unroll
    for (int l = 1; l < 7; l++) {
        a0c[l - 1] = *(const bf16x8*)&wsA[((l * 10 + wv) * 64 + lane) * 8];
        a1c[l - 1] = *(const bf16x8*)&wsA[35840 + ((l * 10 + wv) * 64 + lane) * 8];
    }
    bf16x8 f0c[3], f1c[3];                  // folded A0·Wrh_dx (layer 0)
#pragma unroll
    for (int dx = 0; dx < 3; dx++) {
        f0c[dx] = *(const bf16x8*)&wsA[90112 + ((dx * 10 + wv) * 64 + lane) * 8];
        f1c[dx] = *(const bf16x8*)&wsA[105472 + ((dx * 10 + wv) * 64 + lane) * 8];
    }
    bf16x8 cva0[3], cva1[3];                // Wrc conv (c' producers)
    if (wv >= 3 && wv < 6) {
        int mtc = wv - 3;
#pragma unroll
        for (int dx = 0; dx < 3; dx++) {
            int it = (3 + dx) * 3 + mtc;    // cv=1 tiles
            cva0[dx] = *(const bf16x8*)&wsA[71680 + (it * 64 + lane) * 8];
            cva1[dx] = *(const bf16x8*)&wsA[80896 + (it * 64 + lane) * 8];
        }
    }

    // ---- ONE gate: all conv workers done (bounded; ~10us typical) ----
    if (tid == 0) {
        int gk = 0;
        while (__hip_atomic_load(xcnt, __ATOMIC_ACQUIRE,
                                 __HIP_MEMORY_SCOPE_AGENT) < NWRK) {
            if (++gk > (1 << 17)) break;    // ~28ms guard: fail loud, not hung
            __builtin_amdgcn_s_sleep(8);
        }
    }
    __syncthreads();                        // gate result + cache state shared

    float c_reg = 0.0f;
    const size_t xstride = 10240;   // floats per (b,t)
    const size_t xbase0 = (size_t)(b * 64) * xstride
        + (((size_t)g * 10 + wv) * 4 + q) * 64 + l16 * 4;
    f32x4 xv = *(const f32x4*)&x_ws[xbase0];   // row 0 (plain load, post-gate)

    for (int t = 0; t < 64; t++) {
        // ---- prefetch x for row t+1 (plain load, waited at first use) ----
        f32x4 xn = xv;
        if (t < 63) xn = *(const f32x4*)&x_ws[xbase0 + (size_t)(t + 1) * xstride];

        // ---- c' producers (waves 3-5): conv c, publish via flag ----
        if (wv >= 3 && wv < 6) {
            f32x4 ac = f32x4{0.f, 0.f, 0.f, 0.f};
#pragma unroll
            for (int dx = 0; dx < 3; dx++) {
                bf16x8 b0 = *(const bf16x8*)&cC[(l16 + dx) * STP + q * 8];
                bf16x8 b1 = *(const bf16x8*)&cC[(l16 + dx) * STP + 32 + q * 8];
                ac = __builtin_amdgcn_mfma_f32_16x16x32_bf16(cva0[dx], b0, ac, 0, 0, 0);
                ac = __builtin_amdgcn_mfma_f32_16x16x32_bf16(cva1[dx], b1, ac, 0, 0, 0);
            }
            int mtc = wv - 3, ch0 = 16 * mtc + 4 * q;
            if (ch0 < 40) {
#pragma unroll
                for (int r = 0; r < 4; r++) cwf[(ch0 + r) * CWS + l16] = ac[r];
            }
            __asm__ volatile("s_waitcnt lgkmcnt(0)" ::: "memory");
            if (lane == 0)
                __hip_atomic_store(&cflag[mtc], (unsigned)t,
                                   __ATOMIC_RELAXED, __HIP_MEMORY_SCOPE_WORKGROUP);
        }

        // ---- layer-0 gate MFMAs: folded conv+1x1 straight from hC ----
        f32x4 acc0 = f32x4{0.f, 0.f, 0.f, 0.f};
#pragma unroll
        for (int dx = 0; dx < 3; dx++) {
            bf16x8 b0 = *(const bf16x8*)&hC[(l16 + dx) * STP + q * 8];
            bf16x8 b1 = *(const bf16x8*)&hC[(l16 + dx) * STP + 32 + q * 8];
            acc0 = __builtin_amdgcn_mfma_f32_16x16x32_bf16(f0c[dx], b0, acc0, 0, 0, 0);
            acc0 = __builtin_amdgcn_mfma_f32_16x16x32_bf16(f1c[dx], b1, acc0, 0, 0, 0);
        }
        // ---- wait for c' (usually 0 iterations; intra-block) ----
        {
            int jj = wv >> 2;
            while (__hip_atomic_load(&cflag[jj], __ATOMIC_RELAXED,
                                     __HIP_MEMORY_SCOPE_WORKGROUP) != (unsigned)t)
                __builtin_amdgcn_s_sleep(1);
            __asm__ volatile("" ::: "memory");
        }

        // ---- 7 layers (l0 uses acc0; l1..6 read hL) ----
#pragma unroll
        for (int l = 0; l < 7; l++) {
            f32x4 acc;
            if (l == 0) {
                acc = acc0;
                c_reg = cwf[cc * CWS + l16];
            } else {
                const __bf16* hb = &hL[(l & 1) * HLS];
                bf16x8 b0 = *(const bf16x8*)&hb[l16 * STP + q * 8];
                bf16x8 b1 = *(const bf16x8*)&hb[l16 * STP + 32 + q * 8];
                acc = __builtin_amdgcn_mfma_f32_16x16x32_bf16(
                    a0c[l - 1], b0, f32x4{0.f, 0.f, 0.f, 0.f}, 0, 0, 0);
                acc = __builtin_amdgcn_mfma_f32_16x16x32_bf16(a1c[l - 1], b1, acc, 0, 0, 0);
            }
            float Ei = __builtin_amdgcn_exp2f(fminf(acc[0] + xv[0], 44.f));
            float Ef = __builtin_amdgcn_exp2f(fminf(acc[1] + xv[1], 44.f));
            float Eo = __builtin_amdgcn_exp2f(fminf(acc[2] + xv[2], 44.f));
            float Eg = __builtin_amdgcn_exp2f(fminf(acc[3] + xv[3], 44.f));
            float f = __builtin_amdgcn_rcpf(1.0f + Ef);
            float ig = (1.0f - Eg) * __builtin_amdgcn_rcpf((1.0f + Ei) * (1.0f + Eg));
            float c = __builtin_fmaf(f, c_reg, ig);
            c_reg = c;
            float Ec = __builtin_amdgcn_exp2f(fminf(SC2 * c, 44.f));
            float h = (1.0f - Ec) * __builtin_amdgcn_rcpf((1.0f + Eo) * (1.0f + Ec));
            if (l < 6) {
                hL[((l + 1) & 1) * HLS + l16 * STP + cc] = (__bf16)h;
                BARRIER_LGKM();
            } else {
                hC[(l16 + 1) * STP + cc] = (__bf16)h;
                cC[(l16 + 1) * STP + cc] = (__bf16)c;
                hid_ws[(size_t)((b * 64 + t) * 40 + cc) * 64 + W0 + l16] = h;
                if (t < 63) {
                    unsigned short h16 = __builtin_bit_cast(unsigned short, (__bf16)h);
                    unsigned short c16 = __builtin_bit_cast(unsigned short, (__bf16)c);
                    unsigned long long v = ((unsigned long long)(unsigned)t << 32)
                        | ((unsigned)c16 << 16) | (unsigned)h16;
                    if (l16 == 0 && g > 0)
                        __hip_atomic_store(
                            &halo_ws[((bid * 2 + 0) * 2 + (t & 1)) * 40 + cc], v,
                            __ATOMIC_RELAXED, __HIP_MEMORY_SCOPE_AGENT);
                    if (l16 == 15 && g < 3)
                        __hip_atomic_store(
                            &halo_ws[((bid * 2 + 1) * 2 + (t & 1)) * 40 + cc], v,
                            __ATOMIC_RELAXED, __HIP_MEMORY_SCOPE_AGENT);
                }
                // no barrier here: merged with post-poll barrier below
            }
        }

        // ---- ingest neighbor halos for row t+1 (wv8: left, wv9: right) ----
        if (t < 63) {
            if (wv == 8 && g > 0 && lane < 40) {
                const unsigned long long* src =
                    &halo_ws[(((bid - 16) * 2 + 1) * 2 + (t & 1)) * 40 + lane];
                unsigned long long v = __hip_atomic_load(
                    src, __ATOMIC_RELAXED, __HIP_MEMORY_SCOPE_AGENT);
                while ((unsigned)(v >> 32) != (unsigned)t) {
                    __builtin_amdgcn_s_sleep(1);
                    v = __hip_atomic_load(src, __ATOMIC_RELAXED,
                                          __HIP_MEMORY_SCOPE_AGENT);
                }
                hC[lane] = __builtin_bit_cast(__bf16, (unsigned short)(v & 0xffffu));
                cC[lane] = __builtin_bit_cast(__bf16, (unsigned short)((v >> 16) & 0xffffu));
            }
            if (wv == 9 && g < 3 && lane < 40) {
                const unsigned long long* src =
                    &halo_ws[(((bid + 16) * 2 + 0) * 2 + (t & 1)) * 40 + lane];
                unsigned long long v = __hip_atomic_load(
                    src, __ATOMIC_RELAXED, __HIP_MEMORY_SCOPE_AGENT);
                while ((unsigned)(v >> 32) != (unsigned)t) {
                    __builtin_amdgcn_s_sleep(1);
                    v = __hip_atomic_load(src, __ATOMIC_RELAXED,
                                          __HIP_MEMORY_SCOPE_AGENT);
                }
                hC[17 * STP + lane] = __builtin_bit_cast(__bf16, (unsigned short)(v & 0xffffu));
                cC[17 * STP + lane] = __builtin_bit_cast(__bf16, (unsigned short)((v >> 16) & 0xffffu));
            }
        }
        BARRIER_LGKM();   // single end-of-row barrier (l6 writes + halo cols)
        xv = xn;
    }
}

// ---------------------------------------------------------------------------
__global__ __launch_bounds__(256) void out_kernel(
        const float* __restrict__ hid_ws, const float* __restrict__ w_out,
        const float* __restrict__ b_out, float* __restrict__ out) {
    __shared__ float wlds[40 * 264];   // transposed [k][o]
    __shared__ float hlds[40 * 64];
    int b = blockIdx.x >> 6, y = blockIdx.x & 63;
    int tid = threadIdx.x;
    for (int i = tid; i < 10240; i += 256) {
        int o = i / 40, k = i - o * 40;
        wlds[k * 264 + o] = w_out[i];
    }
    const float* hbp = hid_ws + (size_t)(b * 64 + y) * 40 * 64;
    for (int i = tid; i < 2560; i += 256) hlds[i] = hbp[i];
    __syncthreads();

    int tn = tid & 7, tm = tid >> 3;
    int wbase = tn * 8, obase = tm * 8;
    float acc[8][8];
#pragma unroll
    for (int io = 0; io < 8; io++)
#pragma unroll
        for (int iw = 0; iw < 8; iw++) acc[io][iw] = 0.0f;

    for (int k = 0; k < 40; k++) {
        f32x4 hA = *(const f32x4*)&hlds[k * 64 + wbase];
        f32x4 hB = *(const f32x4*)&hlds[k * 64 + wbase + 4];
        f32x4 wA = *(const f32x4*)&wlds[k * 264 + obase];
        f32x4 wB = *(const f32x4*)&wlds[k * 264 + obase + 4];
#pragma unroll
        for (int io = 0; io < 8; io++) {
            float wo = (io < 4) ? wA[io] : wB[io - 4];
#pragma unroll
            for (int iw = 0; iw < 8; iw++) {
                float hx = (iw < 4) ? hA[iw] : hB[iw - 4];
                acc[io][iw] = __builtin_fmaf(wo, hx, acc[io][iw]);
            }
        }
    }
#pragma unroll
    for (int io = 0; io < 8; io++) {
        int o = obase + io;
        float bo = b_out[o];
        f32x4 s0, s1;
#pragma unroll
        for (int iw = 0; iw < 4; iw++)
            s0[iw] = fmaxf(acc[io][iw] + bo, 0.0f);
#pragma unroll
        for (int iw = 0; iw < 4; iw++)
            s1[iw] = fmaxf(acc[io][iw + 4] + bo, 0.0f);
        float* ob = out + (size_t)((b * 256 + o) * 64 + y) * 64 + wbase;
        *(f32x4*)ob = s0;
        *(f32x4*)(ob + 4) = s1;
    }
}

// ---------------------------------------------------------------------------
extern "C" void kernel_launch(void* const* d_in, const int* in_sizes, int n_in,
                              void* d_out, int out_size, void* d_ws,
                              size_t ws_size, hipStream_t stream) {
    const float* input  = (const float*)d_in[0];
    const float* target = (const float*)d_in[1];
    const float* w_is   = (const float*)d_in[2];
    const float* b_is   = (const float*)d_in[3];
    const float* w_cis  = (const float*)d_in[4];
    const float* b_cis  = (const float*)d_in[5];
    const float* w_rh   = (const float*)d_in[6];
    const float* b_rh   = (const float*)d_in[7];
    const float* w_rc   = (const float*)d_in[8];
    const float* b_rc   = (const float*)d_in[9];
    const float* w_cell = (const float*)d_in[10];
    const float* b_cell = (const float*)d_in[11];
    const float* w_out  = (const float*)d_in[12];
    const float* b_out  = (const float*)d_in[13];
    float* out = (float*)d_out;

    char* ws = (char*)d_ws;
    float*              x_ws    = (float*)ws;                        // 41,943,040 B
    float*              hid_ws  = (float*)(ws + 41943040);           // 10,485,760 B
    __bf16*             wsA     = (__bf16*)(ws + 52428800);          //    241,664 B
    unsigned long long* halo_ws = (unsigned long long*)(ws + 52670464); // 81,920 B
    unsigned*           xcnt    = (unsigned*)(ws + 52752384);        //          4 B

    prep_kernel<<<473, 256, 0, stream>>>(w_cell, w_rh, w_rc, b_cell, b_rh,
                                         b_rc, wsA, xcnt);
    fused_kernel<<<240, 640, 0, stream>>>(input, target, w_is, b_is, w_cis,
                                          b_cis, x_ws, wsA, hid_ws, halo_ws,
                                          xcnt);
    out_kernel<<<1024, 256, 0, stream>>>(hid_ws, w_out, b_out, out);
}

// Round 7
// 366.348 us; speedup vs baseline: 7.0973x; 1.2513x over previous
//
#include <hip/hip_runtime.h>

// ---------------------------------------------------------------------------
// RowLSTM on MI355X — round 13: fold the output GEMM INTO rnn (block-local).
//  - R12 lesson: conv on 176 fat blocks = 3x inefficient (100us) and the
//    all-or-nothing gate serialized rnn behind it. Fusion of conv abandoned;
//    conv7 reverts to the proven 1024-block standalone dispatch.
//  - New insight: rnn block (g,b) produces ALL 40 h-channels for its own 16
//    columns -> out[b,:,y,W0:W0+16] = w_out·h is BLOCK-LOCAL. w_out+b_out are
//    prefolded (prep) into 16 MFMA A-tiles (bias via constant channel
//    h[40]=1, same trick as the cell weights). Waves 0-7 each own 2 o-tiles:
//    per row, 2 shared ds_read_b128 of hC + 4 MFMAs + 8 relu'd stores,
//    computed for row t-1 at the top of iteration t (hC still holds row
//    t-1's h there; the l0->l1 barrier orders reads vs l6 overwrite).
//    Epilogue emits y=63. out_kernel + hid_ws traffic DELETED. No sync added.
// Carried: R8 folded layer-0 + c' flag handshake, STP=56, readfirstlane conv,
// packed 64-bit halo atomics, single end-of-row barrier, x double-buffer in
// regs, exp2-prescaled weights/x, lgkm-only barriers, 64 blocks x 640 thr.
// ---------------------------------------------------------------------------

typedef __bf16 bf16x8 __attribute__((ext_vector_type(8)));
typedef __bf16 bf16x4 __attribute__((ext_vector_type(4)));
typedef float  f32x4  __attribute__((ext_vector_type(4)));

#define SC1 (-1.44269504089f)   // -log2(e)
#define SC2 (-2.88539008178f)   // -2 log2(e)

#define STP 56                   // bf16 elems per state column
#define HLS 896                  // hL per-buffer stride = 16*STP
#define CWS 17                   // cwf leading stride

#define BARRIER_LGKM() __asm__ volatile("s_waitcnt lgkmcnt(0)\ns_barrier" ::: "memory")

// ---------------------------------------------------------------------------
// wsA (bf16 elems):
//  [0     ,35840)  cell a0 : [(l*10+mt)][lane][j]  (l=0 part unused)
//  [35840 ,71680)  cell a1x: k<40 weight, k==40 bias, else 0
//  [71680 ,80896)  conv a0 : [(cv*9+dx*3+mtc)][lane][j] (cv=1 used)
//  [80896 ,90112)  conv a1x
//  [90112 ,105472) F a0  : F_dx = A0·Wrh_dx, scaled
//  [105472,120832) F a1x : k==40&&dx==1 -> s·(A0·b_rh + b_cell0)
//  [120832,129024) out a0 : [ot][lane][j]  o=ot*16+(lane&15), k=0..31, w_out
//  [129024,137216) out a1x: k=32..47; k<40 w_out, k==40 b_out, else 0
__global__ __launch_bounds__(256) void prep_kernel(
        const float* __restrict__ wcell, const float* __restrict__ wrh,
        const float* __restrict__ wrc, const float* __restrict__ bcell,
        const float* __restrict__ brh, const float* __restrict__ brc,
        const float* __restrict__ w_out, const float* __restrict__ b_out,
        __bf16* __restrict__ wsA) {
    int i = blockIdx.x * 256 + threadIdx.x;
    if (i >= 137216) return;
    float val = 0.0f;
    if (i < 35840) {                       // cell a0
        int j = i & 7, lane = (i >> 3) & 63, lm = i >> 9;
        int mt = lm % 10, l = lm / 10;
        int k = (lane >> 4) * 8 + j, m = lane & 15, r = m & 3;
        int row = r * 40 + 4 * mt + (m >> 2);
        val = wcell[(l * 160 + row) * 40 + k] * (r == 3 ? SC2 : SC1);
    } else if (i < 71680) {                // cell a1 ext
        int i2 = i - 35840;
        int j = i2 & 7, lane = (i2 >> 3) & 63, lm = i2 >> 9;
        int mt = lm % 10, l = lm / 10;
        int k = 32 + (lane >> 4) * 8 + j, m = lane & 15, r = m & 3;
        int row = r * 40 + 4 * mt + (m >> 2);
        float s = (r == 3 ? SC2 : SC1);
        if (k < 40)       val = wcell[(l * 160 + row) * 40 + k] * s;
        else if (k == 40) val = bcell[l * 160 + row] * s;
    } else if (i < 80896) {                // conv a0
        int i3 = i - 71680;
        int j = i3 & 7, lane = (i3 >> 3) & 63, idx = i3 >> 9;   // 0..17
        int mtc = idx % 3, t2 = idx / 3, dx = t2 % 3, cv = t2 / 3;
        int k = (lane >> 4) * 8 + j;
        int ch = 16 * mtc + (lane & 15);
        const float* w = cv ? wrc : wrh;       // [40][40][1][3]
        if (ch < 40) val = w[(ch * 40 + k) * 3 + dx];
    } else if (i < 90112) {                // conv a1 ext
        int i4 = i - 80896;
        int j = i4 & 7, lane = (i4 >> 3) & 63, idx = i4 >> 9;
        int mtc = idx % 3, t2 = idx / 3, dx = t2 % 3, cv = t2 / 3;
        int k = 32 + (lane >> 4) * 8 + j;
        int ch = 16 * mtc + (lane & 15);
        if (ch < 40) {
            const float* w = cv ? wrc : wrh;
            if (k < 40)                    val = w[(ch * 40 + k) * 3 + dx];
            else if (k == 40 && dx == 1)   val = (cv ? brc : brh)[ch];
        }
    } else if (i < 105472) {               // F a0: A0·Wrh_dx, k=0..31
        int i5 = i - 90112;
        int j = i5 & 7, lane = (i5 >> 3) & 63, idx = i5 >> 9;   // 0..29
        int mt = idx % 10, dx = idx / 10;
        int k = (lane >> 4) * 8 + j, m = lane & 15, r = m & 3;
        int row = r * 40 + 4 * mt + (m >> 2);
        float s = (r == 3 ? SC2 : SC1);
        float acc = 0.0f;
        for (int mm = 0; mm < 40; mm++)
            acc = __builtin_fmaf(wcell[row * 40 + mm],
                                 wrh[(mm * 40 + k) * 3 + dx], acc);
        val = acc * s;
    } else if (i < 120832) {               // F a1 ext, k=32..47
        int i6 = i - 105472;
        int j = i6 & 7, lane = (i6 >> 3) & 63, idx = i6 >> 9;
        int mt = idx % 10, dx = idx / 10;
        int k = 32 + (lane >> 4) * 8 + j, m = lane & 15, r = m & 3;
        int row = r * 40 + 4 * mt + (m >> 2);
        float s = (r == 3 ? SC2 : SC1);
        if (k < 40) {
            float acc = 0.0f;
            for (int mm = 0; mm < 40; mm++)
                acc = __builtin_fmaf(wcell[row * 40 + mm],
                                     wrh[(mm * 40 + k) * 3 + dx], acc);
            val = acc * s;
        } else if (k == 40 && dx == 1) {
            float acc = bcell[row];        // b_cell0 + A0·b_rh
            for (int mm = 0; mm < 40; mm++)
                acc = __builtin_fmaf(wcell[row * 40 + mm], brh[mm], acc);
            val = acc * s;
        }
    } else if (i < 129024) {               // out a0: w_out, k=0..31
        int i7 = i - 120832;
        int j = i7 & 7, lane = (i7 >> 3) & 63, ot = i7 >> 9;    // 0..15
        int k = (lane >> 4) * 8 + j;
        int o = ot * 16 + (lane & 15);
        val = w_out[o * 40 + k];
    } else {                               // out a1x: k=32..47
        int i8 = i - 129024;
        int j = i8 & 7, lane = (i8 >> 3) & 63, ot = i8 >> 9;
        int k = 32 + (lane >> 4) * 8 + j;
        int o = ot * 16 + (lane & 15);
        if (k < 40)       val = w_out[o * 40 + k];
        else if (k == 40) val = b_out[o];
    }
    wsA[i] = (__bf16)val;
}

// ---------------------------------------------------------------------------
// x_ws (float, PRE-SCALED): [b][t][g4][mt10][q4][l16][gate4]
__global__ __launch_bounds__(256) void conv7_kernel(
        const float* __restrict__ inp, const float* __restrict__ tgt,
        const float* __restrict__ w_is, const float* __restrict__ b_is,
        const float* __restrict__ w_cis, const float* __restrict__ b_cis,
        float* __restrict__ x_ws) {
    int b = blockIdx.x >> 6, y = blockIdx.x & 63;
    int tid = threadIdx.x, qq = tid >> 6, w = tid & 63;
    const float* ib = inp + b * 4096;
    const float* tb = tgt + b * 4096;
    float pin[7][7], ptg[4][7];
#pragma unroll
    for (int dy = 0; dy < 7; dy++) {
        int yy = y + dy - 3;
#pragma unroll
        for (int dx = 0; dx < 7; dx++) {
            int xx = w + dx - 3;
            bool ok = (yy >= 0 && yy < 64 && xx >= 0 && xx < 64);
            pin[dy][dx] = ok ? ib[yy * 64 + xx] : 0.0f;
            if (dy < 4) ptg[dy][dx] = ok ? tb[yy * 64 + xx] : 0.0f;
        }
    }
    int g = w >> 4, l16 = w & 15;
    for (int j = 0; j < 10; j++) {
        int cc = 4 * j + qq;
        // cc is wave-uniform; readfirstlane makes loads provably uniform.
        int ccu = __builtin_amdgcn_readfirstlane(cc);
        float a0 = b_cis[ccu], a1 = b_cis[40 + ccu];
        float a2 = b_is[ccu], a3 = b_is[40 + ccu];
        const float* w0 = w_cis + ccu * 49;
        const float* w1 = w_cis + (40 + ccu) * 49;
        const float* w2 = w_is + ccu * 49;
        const float* w3 = w_is + (40 + ccu) * 49;
#pragma unroll
        for (int dy = 0; dy < 7; dy++)
#pragma unroll
            for (int dx = 0; dx < 7; dx++) {
                a0 = __builtin_fmaf(w0[dy * 7 + dx], pin[dy][dx], a0);
                a1 = __builtin_fmaf(w1[dy * 7 + dx], pin[dy][dx], a1);
            }
#pragma unroll
        for (int dy = 0; dy < 3; dy++)
#pragma unroll
            for (int dx = 0; dx < 7; dx++) {
                a2 = __builtin_fmaf(w2[dy * 7 + dx], ptg[dy][dx], a2);
                a3 = __builtin_fmaf(w3[dy * 7 + dx], ptg[dy][dx], a3);
            }
#pragma unroll
        for (int dx = 0; dx < 3; dx++) {
            a2 = __builtin_fmaf(w2[21 + dx], ptg[3][dx], a2);
            a3 = __builtin_fmaf(w3[21 + dx], ptg[3][dx], a3);
        }
        size_t idx = (size_t)((((b * 64 + y) * 4 + g) * 10 + j) * 4 + qq) * 64
                     + l16 * 4;
        *(f32x4*)&x_ws[idx] = f32x4{a0 * SC1, a1 * SC1, a2 * SC1, a3 * SC2};
    }
}

// ---------------------------------------------------------------------------
// rnn + fused out: 64 blocks, bid = g*16 + b.
// halo_ws (u64): [bid][side2][parity2][ch40]; word = tag<<32 | c16<<16 | h16.
__global__ __launch_bounds__(640, 1) void rnn_kernel(
        const float* __restrict__ x_ws, const __bf16* __restrict__ wsA,
        unsigned long long* __restrict__ halo_ws, float* __restrict__ out) {
    // state, transposed [col 0..17][ch 0..47+pad]; col0/17 = halos; ch40 == 1.0
    __shared__ __align__(16) __bf16 hC[18 * STP + 64];
    __shared__ __align__(16) __bf16 cC[18 * STP + 64];
    __shared__ __align__(16) __bf16 hL[2 * HLS + 32];  // [buf][col][ch]
    __shared__ float cwf[40 * CWS];                    // conv c' fp32
    __shared__ unsigned cflag[4];                      // c' ready flags (tag=t)

    const int bid = blockIdx.x, g = bid >> 4, b = bid & 15;
    const int tid = threadIdx.x, wv = tid >> 6, lane = tid & 63;
    const int q = lane >> 4, l16 = lane & 15, cc = 4 * wv + q;
    const int W0 = g * 16;

    // ---- init LDS ----
    for (int i = tid; i < 536; i += 640) {   // 1072 bf16 = 536 floats
        ((float*)hC)[i] = 0.0f;
        ((float*)cC)[i] = 0.0f;
    }
    for (int i = tid; i < 912; i += 640)     // 1824 bf16 = 912 floats
        ((float*)hL)[i] = 0.0f;
    for (int i = tid; i < 40 * CWS; i += 640) cwf[i] = 0.0f;
    if (tid < 4) cflag[tid] = 0xFFFFFFFFu;
    __syncthreads();                          // zeros done BEFORE ones
    if (tid < 18) { hC[tid * STP + 40] = (__bf16)1.0f; cC[tid * STP + 40] = (__bf16)1.0f; }
    if (tid < 32) hL[(tid >> 4) * HLS + (tid & 15) * STP + 40] = (__bf16)1.0f;
    __syncthreads();

    // ---- preload fragments into registers ----
    bf16x8 a0c[6], a1c[6];                   // cell layers 1..6 (index l-1)
#pragma unroll
    for (int l = 1; l < 7; l++) {
        a0c[l - 1] = *(const bf16x8*)&wsA[((l * 10 + wv) * 64 + lane) * 8];
        a1c[l - 1] = *(const bf16x8*)&wsA[35840 + ((l * 10 + wv) * 64 + lane) * 8];
    }
    bf16x8 f0c[3], f1c[3];                   // folded A0·Wrh_dx (layer 0)
#pragma unroll
    for (int dx = 0; dx < 3; dx++) {
        f0c[dx] = *(const bf16x8*)&wsA[90112 + ((dx * 10 + wv) * 64 + lane) * 8];
        f1c[dx] = *(const bf16x8*)&wsA[105472 + ((dx * 10 + wv) * 64 + lane) * 8];
    }
    bf16x8 cva0[3], cva1[3];                 // Wrc conv (c' producers only)
    if (wv >= 3 && wv < 6) {
        int mtc = wv - 3;
#pragma unroll
        for (int dx = 0; dx < 3; dx++) {
            int it = (3 + dx) * 3 + mtc;     // cv=1 tiles
            cva0[dx] = *(const bf16x8*)&wsA[71680 + (it * 64 + lane) * 8];
            cva1[dx] = *(const bf16x8*)&wsA[80896 + (it * 64 + lane) * 8];
        }
    }
    bf16x8 o0c[2], o1c[2];                   // w_out tiles (waves 0-7, 2 each)
    if (wv < 8) {
#pragma unroll
        for (int tt = 0; tt < 2; tt++) {
            int ot = 2 * wv + tt;
            o0c[tt] = *(const bf16x8*)&wsA[120832 + (ot * 64 + lane) * 8];
            o1c[tt] = *(const bf16x8*)&wsA[129024 + (ot * 64 + lane) * 8];
        }
    }

    float c_reg = 0.0f;
    const size_t xstride = 10240;   // floats per (b,t)
    const size_t xbase0 = (size_t)(b * 64) * xstride
        + (((size_t)g * 10 + wv) * 4 + q) * 64 + l16 * 4;
    f32x4 xv = *(const f32x4*)&x_ws[xbase0];   // row 0

    for (int t = 0; t < 64; t++) {
        // ---- prefetch x for row t+1 (held in regs, waited at first use) ----
        f32x4 xn = xv;
        if (t < 63) xn = *(const f32x4*)&x_ws[xbase0 + (size_t)(t + 1) * xstride];

        // ---- c' producers (waves 3-5): conv c, publish via flag ----
        if (wv >= 3 && wv < 6) {
            f32x4 ac = f32x4{0.f, 0.f, 0.f, 0.f};
#pragma unroll
            for (int dx = 0; dx < 3; dx++) {
                bf16x8 b0 = *(const bf16x8*)&cC[(l16 + dx) * STP + q * 8];
                bf16x8 b1 = *(const bf16x8*)&cC[(l16 + dx) * STP + 32 + q * 8];
                ac = __builtin_amdgcn_mfma_f32_16x16x32_bf16(cva0[dx], b0, ac, 0, 0, 0);
                ac = __builtin_amdgcn_mfma_f32_16x16x32_bf16(cva1[dx], b1, ac, 0, 0, 0);
            }
            int mtc = wv - 3, ch0 = 16 * mtc + 4 * q;
            if (ch0 < 40) {
#pragma unroll
                for (int r = 0; r < 4; r++) cwf[(ch0 + r) * CWS + l16] = ac[r];
            }
            __asm__ volatile("s_waitcnt lgkmcnt(0)" ::: "memory");
            if (lane == 0)
                __hip_atomic_store(&cflag[mtc], (unsigned)t,
                                   __ATOMIC_RELAXED, __HIP_MEMORY_SCOPE_WORKGROUP);
        }

        // ---- layer-0 gate MFMAs: folded conv+1x1 straight from hC ----
        f32x4 acc0 = f32x4{0.f, 0.f, 0.f, 0.f};
#pragma unroll
        for (int dx = 0; dx < 3; dx++) {
            bf16x8 b0 = *(const bf16x8*)&hC[(l16 + dx) * STP + q * 8];
            bf16x8 b1 = *(const bf16x8*)&hC[(l16 + dx) * STP + 32 + q * 8];
            acc0 = __builtin_amdgcn_mfma_f32_16x16x32_bf16(f0c[dx], b0, acc0, 0, 0, 0);
            acc0 = __builtin_amdgcn_mfma_f32_16x16x32_bf16(f1c[dx], b1, acc0, 0, 0, 0);
        }

        // ---- fused OUT for row t-1 (hC cols 1..16 still hold row t-1's h;
        //      the l0->l1 barrier below orders these reads vs l6 overwrite) ----
        if (t > 0 && wv < 8) {
            int y = t - 1;
            bf16x8 bo0 = *(const bf16x8*)&hC[(l16 + 1) * STP + q * 8];
            bf16x8 bo1 = *(const bf16x8*)&hC[(l16 + 1) * STP + 32 + q * 8];
#pragma unroll
            for (int tt = 0; tt < 2; tt++) {
                f32x4 oa = __builtin_amdgcn_mfma_f32_16x16x32_bf16(
                    o0c[tt], bo0, f32x4{0.f, 0.f, 0.f, 0.f}, 0, 0, 0);
                oa = __builtin_amdgcn_mfma_f32_16x16x32_bf16(o1c[tt], bo1, oa, 0, 0, 0);
                int o0 = (2 * wv + tt) * 16 + 4 * q;
#pragma unroll
                for (int r = 0; r < 4; r++)
                    out[((size_t)(b * 256 + o0 + r) * 64 + y) * 64 + W0 + l16] =
                        fmaxf(oa[r], 0.0f);
            }
        }

        // ---- wait for c' (usually 0 iterations) ----
        {
            int jj = wv >> 2;
            while (__hip_atomic_load(&cflag[jj], __ATOMIC_RELAXED,
                                     __HIP_MEMORY_SCOPE_WORKGROUP) != (unsigned)t)
                __builtin_amdgcn_s_sleep(1);
            __asm__ volatile("" ::: "memory");
        }

        // ---- 7 layers (l0 uses acc0; l1..6 read hL) ----
#pragma unroll
        for (int l = 0; l < 7; l++) {
            f32x4 acc;
            if (l == 0) {
                acc = acc0;
                c_reg = cwf[cc * CWS + l16];
            } else {
                const __bf16* hb = &hL[(l & 1) * HLS];
                bf16x8 b0 = *(const bf16x8*)&hb[l16 * STP + q * 8];
                bf16x8 b1 = *(const bf16x8*)&hb[l16 * STP + 32 + q * 8];
                acc = __builtin_amdgcn_mfma_f32_16x16x32_bf16(
                    a0c[l - 1], b0, f32x4{0.f, 0.f, 0.f, 0.f}, 0, 0, 0);
                acc = __builtin_amdgcn_mfma_f32_16x16x32_bf16(a1c[l - 1], b1, acc, 0, 0, 0);
            }
            float Ei = __builtin_amdgcn_exp2f(fminf(acc[0] + xv[0], 44.f));
            float Ef = __builtin_amdgcn_exp2f(fminf(acc[1] + xv[1], 44.f));
            float Eo = __builtin_amdgcn_exp2f(fminf(acc[2] + xv[2], 44.f));
            float Eg = __builtin_amdgcn_exp2f(fminf(acc[3] + xv[3], 44.f));
            float f = __builtin_amdgcn_rcpf(1.0f + Ef);
            float ig = (1.0f - Eg) * __builtin_amdgcn_rcpf((1.0f + Ei) * (1.0f + Eg));
            float c = __builtin_fmaf(f, c_reg, ig);
            c_reg = c;
            float Ec = __builtin_amdgcn_exp2f(fminf(SC2 * c, 44.f));
            float h = (1.0f - Ec) * __builtin_amdgcn_rcpf((1.0f + Eo) * (1.0f + Ec));
            if (l < 6) {
                hL[((l + 1) & 1) * HLS + l16 * STP + cc] = (__bf16)h;
                BARRIER_LGKM();
            } else {
                hC[(l16 + 1) * STP + cc] = (__bf16)h;
                cC[(l16 + 1) * STP + cc] = (__bf16)c;
                if (t < 63) {
                    unsigned short h16 = __builtin_bit_cast(unsigned short, (__bf16)h);
                    unsigned short c16 = __builtin_bit_cast(unsigned short, (__bf16)c);
                    unsigned long long v = ((unsigned long long)(unsigned)t << 32)
                        | ((unsigned)c16 << 16) | (unsigned)h16;
                    if (l16 == 0 && g > 0)
                        __hip_atomic_store(
                            &halo_ws[((bid * 2 + 0) * 2 + (t & 1)) * 40 + cc], v,
                            __ATOMIC_RELAXED, __HIP_MEMORY_SCOPE_AGENT);
                    if (l16 == 15 && g < 3)
                        __hip_atomic_store(
                            &halo_ws[((bid * 2 + 1) * 2 + (t & 1)) * 40 + cc], v,
                            __ATOMIC_RELAXED, __HIP_MEMORY_SCOPE_AGENT);
                }
                // no barrier here: merged with post-poll barrier below
            }
        }

        // ---- ingest neighbor halos for row t+1 (wv8: left, wv9: right) ----
        if (t < 63) {
            if (wv == 8 && g > 0 && lane < 40) {
                const unsigned long long* src =
                    &halo_ws[(((bid - 16) * 2 + 1) * 2 + (t & 1)) * 40 + lane];
                unsigned long long v = __hip_atomic_load(
                    src, __ATOMIC_RELAXED, __HIP_MEMORY_SCOPE_AGENT);
                while ((unsigned)(v >> 32) != (unsigned)t) {
                    __builtin_amdgcn_s_sleep(1);
                    v = __hip_atomic_load(src, __ATOMIC_RELAXED,
                                          __HIP_MEMORY_SCOPE_AGENT);
                }
                hC[lane] = __builtin_bit_cast(__bf16, (unsigned short)(v & 0xffffu));
                cC[lane] = __builtin_bit_cast(__bf16, (unsigned short)((v >> 16) & 0xffffu));
            }
            if (wv == 9 && g < 3 && lane < 40) {
                const unsigned long long* src =
                    &halo_ws[(((bid + 16) * 2 + 0) * 2 + (t & 1)) * 40 + lane];
                unsigned long long v = __hip_atomic_load(
                    src, __ATOMIC_RELAXED, __HIP_MEMORY_SCOPE_AGENT);
                while ((unsigned)(v >> 32) != (unsigned)t) {
                    __builtin_amdgcn_s_sleep(1);
                    v = __hip_atomic_load(src, __ATOMIC_RELAXED,
                                          __HIP_MEMORY_SCOPE_AGENT);
                }
                hC[17 * STP + lane] = __builtin_bit_cast(__bf16, (unsigned short)(v & 0xffffu));
                cC[17 * STP + lane] = __builtin_bit_cast(__bf16, (unsigned short)((v >> 16) & 0xffffu));
            }
        }
        BARRIER_LGKM();   // single end-of-row barrier (l6 writes + halo cols)
        xv = xn;
    }

    // ---- epilogue: OUT for row 63 (hC final state, post-barrier) ----
    if (wv < 8) {
        bf16x8 bo0 = *(const bf16x8*)&hC[(l16 + 1) * STP + q * 8];
        bf16x8 bo1 = *(const bf16x8*)&hC[(l16 + 1) * STP + 32 + q * 8];
#pragma unroll
        for (int tt = 0; tt < 2; tt++) {
            f32x4 oa = __builtin_amdgcn_mfma_f32_16x16x32_bf16(
                o0c[tt], bo0, f32x4{0.f, 0.f, 0.f, 0.f}, 0, 0, 0);
            oa = __builtin_amdgcn_mfma_f32_16x16x32_bf16(o1c[tt], bo1, oa, 0, 0, 0);
            int o0 = (2 * wv + tt) * 16 + 4 * q;
#pragma unroll
            for (int r = 0; r < 4; r++)
                out[((size_t)(b * 256 + o0 + r) * 64 + 63) * 64 + W0 + l16] =
                    fmaxf(oa[r], 0.0f);
        }
    }
}

// ---------------------------------------------------------------------------
extern "C" void kernel_launch(void* const* d_in, const int* in_sizes, int n_in,
                              void* d_out, int out_size, void* d_ws,
                              size_t ws_size, hipStream_t stream) {
    const float* input  = (const float*)d_in[0];
    const float* target = (const float*)d_in[1];
    const float* w_is   = (const float*)d_in[2];
    const float* b_is   = (const float*)d_in[3];
    const float* w_cis  = (const float*)d_in[4];
    const float* b_cis  = (const float*)d_in[5];
    const float* w_rh   = (const float*)d_in[6];
    const float* b_rh   = (const float*)d_in[7];
    const float* w_rc   = (const float*)d_in[8];
    const float* b_rc   = (const float*)d_in[9];
    const float* w_cell = (const float*)d_in[10];
    const float* b_cell = (const float*)d_in[11];
    const float* w_out  = (const float*)d_in[12];
    const float* b_out  = (const float*)d_in[13];
    float* out = (float*)d_out;

    char* ws = (char*)d_ws;
    float*              x_ws    = (float*)ws;                        // 41,943,040 B
    __bf16*             wsA     = (__bf16*)(ws + 41943040);          //    274,432 B
    unsigned long long* halo_ws = (unsigned long long*)(ws + 42217472); // 81,920 B

    prep_kernel<<<536, 256, 0, stream>>>(w_cell, w_rh, w_rc, b_cell, b_rh,
                                         b_rc, w_out, b_out, wsA);
    conv7_kernel<<<1024, 256, 0, stream>>>(input, target, w_is, b_is, w_cis,
                                           b_cis, x_ws);
    rnn_kernel<<<64, 640, 0, stream>>>(x_ws, wsA, halo_ws, out);
}